// Round 30
// baseline (119.428 us; speedup 1.0000x reference)
//
#include <hip/hip_runtime.h>
#include <math.h>

// ASFF_2: N=8, C1=256, C2=512, H=64, W=64, low-res 32x32.
// CARAFE-commutation: u = CARAFE(z)+b_up with z = w_up@in2 (low-res GEMM);
// v2 = CARAFE(zw)+c2 with zw = w_l2@z, c2 = w_l2@b_up.
//  prep_in2t (merged ROOTS): in2t + weight transposes + rings + bn
//  lowres_gemm (merged + v1 hoist): bid<192 -> GEMM (zbfT / ktT);
//      bid>=192 -> v1buf = reduce(w_l1 @ input1)  [fills the 64 idle CUs]
//  encsm_zw (merged dispatch): enc MFMA+softmax -> maskb ; zw = w_l2@z
//  carafe_fuse_blend: lw0 WAVE-PARALLEL (256 threads: pixel=tid>>3, j=tid&7,
//      8-lane shfl reduce — was tid<32 serial section) ; pass2 CARAFE+blend
//  K7: m97 GEMM, round-11 pre-barrier triple-buffer schedule (53.1us ceiling).

#define EPS 1e-5f
typedef unsigned short u16;
typedef __attribute__((ext_vector_type(8))) __bf16 bf16x8;
typedef __attribute__((ext_vector_type(4))) float f32x4;

#define VMCNT(N) asm volatile("s_waitcnt vmcnt(" #N ")" ::: "memory")

__device__ inline u16 f2bf(float x) {
    union { float f; unsigned u; } v; v.f = x;
    unsigned r = v.u + 0x7FFF + ((v.u >> 16) & 1);
    return (u16)(r >> 16);
}
__device__ inline float bf2f(u16 x) {
    union { unsigned u; float f; } v; v.u = (unsigned)x << 16; return v.f;
}

// ---------------- staging macros ----------------
#define STAGE_A(dstp, t, kx)                                                         \
    {                                                                                \
        const u16* Abase = A + ((long)(t) * 256 + rowBase) * KCC + (kx) * 32;        \
        _Pragma("unroll")                                                            \
        for (int ii = 0; ii < 2; ++ii) {                                             \
            int f = ii * 256 + tid;                                                  \
            int r = f >> 2, uu = f & 3;                                              \
            __builtin_amdgcn_global_load_lds(                                        \
                (const __attribute__((address_space(1))) void*)                      \
                    (Abase + (long)r * KCC + ((uu ^ ((r >> 1) & 3)) << 3)),          \
                (__attribute__((address_space(3))) void*)((dstp) + f * 8),           \
                16, 0, 0);                                                           \
        }                                                                            \
    }

#define STAGE_B(dstp, kx)                                                            \
    {                                                                                \
        const u16* Bbase = Bn + (long)g0 * KCC + (kx) * 32;                          \
        for (int f = tid; f < BUNITS; f += 256) {                                    \
            int r = f >> 2, uu = f & 3;                                              \
            __builtin_amdgcn_global_load_lds(                                        \
                (const __attribute__((address_space(1))) void*)                      \
                    (Bbase + (long)r * KCC + ((uu ^ ((r >> 1) & 3)) << 3)),          \
                (__attribute__((address_space(3))) void*)((dstp) + f * 8),           \
                16, 0, 0);                                                           \
        }                                                                            \
    }

// ---------------- lowres_gemm (merged zgemm + down_mfma + hoisted v1 pass) ----------------
__global__ __launch_bounds__(256, 2) void lowres_gemm_kernel(
    const u16* __restrict__ Aup,    // wupT [256][512]
    const u16* __restrict__ Adn,    // wdT  [128][512]
    const u16* __restrict__ B,      // in2T [n][1024][512]
    const float* __restrict__ bias, // b_down
    const float* __restrict__ i1g, const float* __restrict__ w_l1,
    u16* __restrict__ Z,            // zbfT [n][1024][256]
    u16* __restrict__ ktT,          // [n][1156][128] padded
    float* __restrict__ v1buf)      // [n][4096][8] fp32
{
    constexpr int KCC = 512;
    constexpr int BUNITS = 512;
    __shared__ __align__(16) u16 lsA[3][128 * 32];
    __shared__ __align__(16) u16 lsB[3][128 * 32];
    const int bid0 = blockIdx.x;
    const int tid = threadIdx.x;

    if (bid0 >= 192) {                  // ---- v1 branch (fills idle CUs) ----
        float* red = (float*)lsA;       // 8KB scratch in the 24KB lsA
        const int vb = bid0 - 192;      // 0..1023
        const int n = vb >> 7;
        const int hw = vb & 127;
        const int h = hw >> 1;
        const int w0 = (hw & 1) << 5;
        const int w = tid & 31;
        const int chunk = tid >> 5;
        const float* i1 = i1g + (long)n * 256 * 4096 + (h << 6) + w0 + w;
        float s1[8] = {};
        for (int i = 0; i < 32; ++i) {
            const int ci = chunk * 32 + i;
            float x1 = i1[(long)ci * 4096];
#pragma unroll
            for (int j = 0; j < 8; ++j) s1[j] += w_l1[j * 256 + ci] * x1;
        }
#pragma unroll
        for (int j = 0; j < 8; ++j) red[(chunk * 32 + w) * 8 + j] = s1[j];
        __syncthreads();
        const int px = tid >> 3, j = tid & 7;
        float s = 0.f;
#pragma unroll
        for (int o = 0; o < 8; ++o) s += red[(o * 32 + px) * 8 + j];
        v1buf[((long)n * 4096 + (h << 6) + w0 + px) * 8 + j] = s;
        return;
    }

    // ---- GEMM branch ----
    const int xb = bid0 & 7;
    const int ybr = (bid0 >> 3) % 3;
    const int n = bid0 / 24;
    const u16* Bn = B + (long)n * 1024 * 512;
    const int lane = tid & 63;
    const int wid = tid >> 6;
    const int mw = wid >> 1, nw = wid & 1;
    const int lr = lane & 15, lk = lane >> 4;
    const u16* A = (ybr < 2) ? Aup : Adn;
    const int rowBase = (ybr < 2) ? ybr * 128 : 0;
    const int colBase = xb * 128;
    const int g0 = colBase;

    STAGE_A(lsA[0], 0, 0); STAGE_B(lsB[0], 0);
    STAGE_A(lsA[1], 0, 1); STAGE_B(lsB[1], 1);

    const int aswz = (lk ^ ((lr >> 1) & 3)) << 3;
    int aoff[4];
#pragma unroll
    for (int mf = 0; mf < 4; ++mf)
        aoff[mf] = (mw * 64 + mf * 16 + lr) * 32 + aswz;

    f32x4 acc[4][4] = {};
    for (int kx = 0; kx < 16; ++kx) {
        if (kx == 15) { VMCNT(0); } else { VMCNT(4); }
        __builtin_amdgcn_s_barrier();
        asm volatile("" ::: "memory");
        if (kx + 2 < 16) {
            STAGE_A(lsA[(kx + 2) % 3], 0, kx + 2);
            STAGE_B(lsB[(kx + 2) % 3], kx + 2);
        }
        const u16* la = lsA[kx % 3];
        const u16* lb = lsB[kx % 3];
        bf16x8 af[4], bfr[4];
#pragma unroll
        for (int mf = 0; mf < 4; ++mf)
            af[mf] = *(const bf16x8*)(la + aoff[mf]);
        const int rb = nw * 64 + lr;
        const int bswz = (lk ^ ((rb >> 1) & 3)) << 3;
#pragma unroll
        for (int nf = 0; nf < 4; ++nf)
            bfr[nf] = *(const bf16x8*)(lb + (rb + nf * 16) * 32 + bswz);
#pragma unroll
        for (int mf = 0; mf < 4; ++mf)
#pragma unroll
            for (int nf = 0; nf < 4; ++nf)
                acc[mf][nf] = __builtin_amdgcn_mfma_f32_16x16x32_bf16(
                    af[mf], bfr[nf], acc[mf][nf], 0, 0, 0);
    }

    if (ybr < 2) {
        u16* Zn = Z + (long)n * 1024 * 256;
#pragma unroll
        for (int mf = 0; mf < 4; ++mf) {
            const int co0 = rowBase + mw * 64 + mf * 16 + lk * 4;
#pragma unroll
            for (int nf = 0; nf < 4; ++nf) {
                const int col = colBase + nw * 64 + nf * 16 + lr;
                unsigned lo = (unsigned)f2bf(acc[mf][nf][0]) |
                              ((unsigned)f2bf(acc[mf][nf][1]) << 16);
                unsigned hi = (unsigned)f2bf(acc[mf][nf][2]) |
                              ((unsigned)f2bf(acc[mf][nf][3]) << 16);
                *(uint2*)(Zn + (long)col * 256 + co0) = make_uint2(lo, hi);
            }
        }
    } else {
        u16* Kn = ktT + (long)n * 1156 * 128;
#pragma unroll
        for (int mf = 0; mf < 4; ++mf) {
            const int co0 = mw * 64 + mf * 16 + lk * 4;     // 0..124
            float b0 = bias[co0], b1 = bias[co0 + 1], b2 = bias[co0 + 2], b3 = bias[co0 + 3];
#pragma unroll
            for (int nf = 0; nf < 4; ++nf) {
                const int col = colBase + nw * 64 + nf * 16 + lr;   // 0..1023
                const int pr = ((col >> 5) + 1) * 34 + (col & 31) + 1;
                unsigned lo = (unsigned)f2bf(acc[mf][nf][0] + b0) |
                              ((unsigned)f2bf(acc[mf][nf][1] + b1) << 16);
                unsigned hi = (unsigned)f2bf(acc[mf][nf][2] + b2) |
                              ((unsigned)f2bf(acc[mf][nf][3] + b3) << 16);
                *(uint2*)(Kn + (long)pr * 128 + co0) = make_uint2(lo, hi);
            }
        }
    }
}

// ---------------- encsm_zw: merged enc-softmax (bid<512) + zw (bid>=512) ----------------
__global__ __launch_bounds__(64) void encsm_zw_kernel(
    const u16* __restrict__ A, const u16* __restrict__ B,   // wencT, ktT
    const float* __restrict__ bias,                         // b_enc
    const u16* __restrict__ zbfT, const float* __restrict__ wl2T,
    float* __restrict__ mask, float* __restrict__ zwT)
{
    const int bid = blockIdx.x;
    const int lane = threadIdx.x;
    if (bid < 512) {
        const int n = bid >> 6;
        const int lr = lane & 15, lk = lane >> 4;
        const int p = (bid & 63) * 16 + lr;
        const int pr = ((p >> 5) + 1) * 34 + (p & 31) + 1;
        const u16* Bn = B + (long)n * 1156 * 128;
        const int bOff = pr * 128 + lk * 8;
        f32x4 acc[3] = {};
        for (int t = 0; t < 9; ++t) {
            const u16* At = A + t * 8192;
            const int btap = ((t / 3 - 1) * 34 + (t % 3 - 1)) * 128;
#pragma unroll
            for (int k0 = 0; k0 < 128; k0 += 32) {
                bf16x8 bf = *(const bf16x8*)(Bn + bOff + btap + k0);
#pragma unroll
                for (int mf = 0; mf < 3; ++mf) {
                    bf16x8 af = *(const bf16x8*)(At + (mf * 16 + lr) * 128 + lk * 8 + k0);
                    acc[mf] = __builtin_amdgcn_mfma_f32_16x16x32_bf16(af, bf, acc[mf], 0, 0, 0);
                }
            }
        }
        float* mp = mask + ((long)n * 1024 + p) * 36;
#pragma unroll
        for (int q = 0; q < 4; ++q) {
            float v0 = acc[0][q] + bias[lk * 4 + q];            // k = lk
            float v1 = acc[1][q] + bias[16 + lk * 4 + q];       // k = 4 + lk
            float v2 = (lk == 0) ? (acc[2][q] + bias[32 + q]) : -1e30f;   // k = 8
            float m = fmaxf(fmaxf(v0, v1), v2);
            m = fmaxf(m, __shfl_xor(m, 16, 64));
            m = fmaxf(m, __shfl_xor(m, 32, 64));
            float e0 = expf(v0 - m);
            float e1 = expf(v1 - m);
            float e2 = (lk == 0) ? expf(v2 - m) : 0.f;
            float s = e0 + e1 + e2;
            s += __shfl_xor(s, 16, 64);
            s += __shfl_xor(s, 32, 64);
            float inv = 1.f / s;
            mp[lk * 4 + q] = e0 * inv;
            mp[16 + lk * 4 + q] = e1 * inv;
            if (lk == 0) mp[32 + q] = e2 * inv;
        }
    } else {
        const int Q = bid - 512;            // 0..8191
        const int ci0 = lane * 4;
        uint2 v = *(const uint2*)(zbfT + (long)Q * 256 + ci0);
        float c[4] = { bf2f((u16)(v.x & 0xffff)), bf2f((u16)(v.x >> 16)),
                       bf2f((u16)(v.y & 0xffff)), bf2f((u16)(v.y >> 16)) };
        float s[8] = {};
#pragma unroll
        for (int t = 0; t < 4; ++t) {
            const float* wr = wl2T + (ci0 + t) * 8;
            float4 wa = *(const float4*)wr;
            float4 wb = *(const float4*)(wr + 4);
            s[0] += wa.x * c[t]; s[1] += wa.y * c[t]; s[2] += wa.z * c[t]; s[3] += wa.w * c[t];
            s[4] += wb.x * c[t]; s[5] += wb.y * c[t]; s[6] += wb.z * c[t]; s[7] += wb.w * c[t];
        }
#pragma unroll
        for (int off = 1; off < 64; off <<= 1)
#pragma unroll
            for (int j = 0; j < 8; ++j)
                s[j] += __shfl_xor(s[j], off, 64);
        if (lane == 0) {
            float* o = zwT + (long)Q * 8;
            *(float4*)o = make_float4(s[0], s[1], s[2], s[3]);
            *(float4*)(o + 4) = make_float4(s[4], s[5], s[6], s[7]);
        }
    }
}

// ---------------- carafe_fuse_blend: wave-parallel lw0 ; pass2 CARAFE+blend ----------------
__global__ __launch_bounds__(256) void carafe_fuse_blend_kernel(
    const float* __restrict__ i1g, const u16* __restrict__ zbfT,
    const float* __restrict__ zwT, const float* __restrict__ maskb,
    const float* __restrict__ bnp,          // 512..519 c2, 768.. b_up
    const float* __restrict__ v1buf, const float* __restrict__ bn_l1,
    const float* __restrict__ bn_l2, const float* __restrict__ w_wl,
    const float* __restrict__ b_wl, u16* __restrict__ dst)
{
    __shared__ float lw0s[32];
    __shared__ __align__(16) u16 lds2[32 * 264];    // 16.5 KB
    const int n = blockIdx.y;
    const int h = blockIdx.x >> 1;
    const int w0 = (blockIdx.x & 1) << 5;
    const int hq = h >> 1;
    const int tid = threadIdx.x;
    const int w = tid & 31;
    const int chunk = tid >> 5;

    {   // lw0: WAVE-PARALLEL — pixel = tid>>3 (32), j = tid&7 (8 channels);
        // 8-lane shfl_xor reduce for z0/z1 (was a tid<32 serial section).
        const int px = tid >> 3;
        const int j  = tid & 7;
        const int wp = w0 + px;
        const int wq = wp >> 1;
        const int q = ((h & 1) << 1) | (wp & 1);
        const float* mrow = maskb + ((long)n * 1024 + hq * 32 + wq) * 36;
        float vj  = v1buf[((long)n * 4096 + (h << 6) + wp) * 8 + j];
        float v8j = bnp[512 + j];       // c2
#pragma unroll
        for (int k = 0; k < 9; ++k) {
            int dh = k / 3 - 1, dw = k - (k / 3) * 3 - 1;
            int gr = hq + dh, gc = wq + dw;
            bool ok = (gr >= 0 && gr < 32 && gc >= 0 && gc < 32);
            float mk = ok ? mrow[k * 4 + q] : 0.f;
            const float* zp = zwT + ((long)n * 1024 +
                                     (ok ? gr * 32 + gc : hq * 32 + wq)) * 8;
            v8j += mk * zp[j];
        }
        float g = bn_l1[j], b = bn_l1[8 + j], m = bn_l1[16 + j], va = bn_l1[24 + j];
        float y = (vj - m) * (g * rsqrtf(va + EPS)) + b;
        float sv = y / (1.f + expf(-y));
        float z0 = w_wl[j] * sv;
        float z1 = w_wl[16 + j] * sv;
        g = bn_l2[j]; b = bn_l2[8 + j]; m = bn_l2[16 + j]; va = bn_l2[24 + j];
        y = (v8j - m) * (g * rsqrtf(va + EPS)) + b;
        sv = y / (1.f + expf(-y));
        z0 += w_wl[8 + j] * sv;
        z1 += w_wl[24 + j] * sv;
#pragma unroll
        for (int off = 1; off < 8; off <<= 1) {
            z0 += __shfl_xor(z0, off, 64);
            z1 += __shfl_xor(z1, off, 64);
        }
        if (j == 0)
            lw0s[px] = 1.f / (1.f + expf((z1 + b_wl[1]) - (z0 + b_wl[0])));
    }
    __syncthreads();
    {   // pass2: u = CARAFE(z from L2)+b_up ; blend (i1 L3-hot) ; bf16 into lds2
        const float lw = lw0s[w], lw1 = 1.f - lw;
        const int wp = w0 + w;
        const int wq = wp >> 1;
        const int q = ((h & 1) << 1) | (wp & 1);
        const float* i1 = i1g + (long)n * 256 * 4096 + (h << 6) + w0 + w;
        const float* mrow = maskb + ((long)n * 1024 + hq * 32 + wq) * 36;
        float m9[9];
        const u16* zp[9];
#pragma unroll
        for (int k = 0; k < 9; ++k) {
            int dh = k / 3 - 1, dw = k - (k / 3) * 3 - 1;
            int gr = hq + dh, gc = wq + dw;
            bool ok = (gr >= 0 && gr < 32 && gc >= 0 && gc < 32);
            m9[k] = ok ? mrow[k * 4 + q] : 0.f;
            zp[k] = zbfT + ((long)n * 1024 +
                            (ok ? gr * 32 + gc : hq * 32 + wq)) * 256;
        }
        for (int ci = chunk * 32; ci < chunk * 32 + 32; ci += 8) {
            float uu[8];
            {
                float4 ba = *(const float4*)(bnp + 768 + ci);
                float4 bb = *(const float4*)(bnp + 768 + ci + 4);
                uu[0] = ba.x; uu[1] = ba.y; uu[2] = ba.z; uu[3] = ba.w;
                uu[4] = bb.x; uu[5] = bb.y; uu[6] = bb.z; uu[7] = bb.w;
            }
#pragma unroll
            for (int k = 0; k < 9; ++k) {
                uint4 vz = *(const uint4*)(zp[k] + ci);
                float mk = m9[k];
                uu[0] += mk * bf2f((u16)(vz.x & 0xffff));
                uu[1] += mk * bf2f((u16)(vz.x >> 16));
                uu[2] += mk * bf2f((u16)(vz.y & 0xffff));
                uu[3] += mk * bf2f((u16)(vz.y >> 16));
                uu[4] += mk * bf2f((u16)(vz.z & 0xffff));
                uu[5] += mk * bf2f((u16)(vz.z >> 16));
                uu[6] += mk * bf2f((u16)(vz.w & 0xffff));
                uu[7] += mk * bf2f((u16)(vz.w >> 16));
            }
            unsigned o0 = (unsigned)f2bf(i1[(long)ci * 4096] * lw + uu[0] * lw1)
                        | ((unsigned)f2bf(i1[(long)(ci + 1) * 4096] * lw + uu[1] * lw1) << 16);
            unsigned o1 = (unsigned)f2bf(i1[(long)(ci + 2) * 4096] * lw + uu[2] * lw1)
                        | ((unsigned)f2bf(i1[(long)(ci + 3) * 4096] * lw + uu[3] * lw1) << 16);
            unsigned o2 = (unsigned)f2bf(i1[(long)(ci + 4) * 4096] * lw + uu[4] * lw1)
                        | ((unsigned)f2bf(i1[(long)(ci + 5) * 4096] * lw + uu[5] * lw1) << 16);
            unsigned o3 = (unsigned)f2bf(i1[(long)(ci + 6) * 4096] * lw + uu[6] * lw1)
                        | ((unsigned)f2bf(i1[(long)(ci + 7) * 4096] * lw + uu[7] * lw1) << 16);
            *(uint4*)(lds2 + w * 264 + ci) = make_uint4(o0, o1, o2, o3);
        }
    }
    __syncthreads();
    {   // transposed padded write
        const int px = tid >> 3, qd = tid & 7;
        const int pg = (h << 6) + w0 + px;
        long prow = (long)((pg >> 6) + 1) * 66 + (pg & 63) + 1;
        u16* drow = dst + (long)n * 4356 * 256 + prow * 256;
        const u16* lrow = lds2 + px * 264;
#pragma unroll
        for (int j = 0; j < 16; ++j) {
            int off = j * 16 + qd * 2;
            *(unsigned*)(drow + off) = *(const unsigned*)(lrow + off);
        }
    }
}

// ---------------- K7: m97 GEMM — round-11 pre-barrier triple-buffer (measured 53.1us) ----------------
template<int KCC, int NT, bool PADDED>
__global__ __launch_bounds__(256, 2) void gemm_m97_kernel(
    const u16* __restrict__ A,      // [NT][256][KCC] bf16
    const u16* __restrict__ B,      // per image [rows][KCC] bf16
    const float* __restrict__ scale, const float* __restrict__ shift,
    float* __restrict__ C, long strideB, long strideC, int silu)
{
    constexpr int RROWS = PADDED ? 264 : 128;
    constexpr int BUNITS = RROWS * 4;
    constexpr int NKX = KCC / 32;
    constexpr int MINB = BUNITS / 256;      // 4 (K7)
    __shared__ __align__(16) u16 lsA[3][128 * 32];
    __shared__ __align__(16) u16 lsB[3][RROWS * 32];
    const int n = blockIdx.z;
    const u16* Bn = B + (long)n * strideB;
    float* Cn = C + (long)n * strideC;
    const int tid = threadIdx.x;
    const int lane = tid & 63;
    const int wid = tid >> 6;
    const int mw = wid >> 1, nw = wid & 1;
    const int lr = lane & 15, lk = lane >> 4;
    const int rowBase = blockIdx.y * 128;
    const int colBase = blockIdx.x * 128;
    const int g0 = PADDED ? (colBase >> 6) * 66 : colBase;

    STAGE_B(lsB[0], 0);
    STAGE_A(lsA[0], 0, 0);

    const int aswz = (lk ^ ((lr >> 1) & 3)) << 3;
    int aoff[4];
#pragma unroll
    for (int mf = 0; mf < 4; ++mf)
        aoff[mf] = (mw * 64 + mf * 16 + lr) * 32 + aswz;

    f32x4 acc[4][4] = {};
    for (int kx = 0; kx < NKX; ++kx) {
        const u16* lb = lsB[kx % 3];
#pragma unroll
        for (int t = 0; t < NT; ++t) {
            const int s = kx * NT + t;
            const bool lastS = (kx == NKX - 1) && (t == NT - 1);
            const bool stgB = (t == 0) && (kx + 1 < NKX);
            if (stgB) STAGE_B(lsB[(kx + 1) % 3], kx + 1);
            if (!lastS) {
                const int t1 = (t + 1 == NT) ? 0 : t + 1;
                const int kx1 = (t + 1 == NT) ? kx + 1 : kx;
                STAGE_A(lsA[(s + 1) % 3], t1, kx1);
            }
            // counted wait: N = loads issued THIS phase (min over threads)
            if (lastS) { VMCNT(0); }
            else if (stgB) { if constexpr (MINB == 2) VMCNT(4); else VMCNT(6); }
            else { VMCNT(2); }
            __builtin_amdgcn_s_barrier();
            asm volatile("" ::: "memory");

            const u16* la = lsA[s % 3];
            bf16x8 af[4], bfr[4];
#pragma unroll
            for (int mf = 0; mf < 4; ++mf)
                af[mf] = *(const bf16x8*)(la + aoff[mf]);
            int rb;
            if (PADDED) {
                int dh = t / 3 - 1, dw = t - (t / 3) * 3 - 1;
                rb = (nw + dh + 1) * 66 + dw + 1 + lr;
            } else {
                rb = nw * 64 + lr;
            }
            const int bswz = (lk ^ ((rb >> 1) & 3)) << 3;
#pragma unroll
            for (int nf = 0; nf < 4; ++nf)
                bfr[nf] = *(const bf16x8*)(lb + (rb + nf * 16) * 32 + bswz);
#pragma unroll
            for (int mf = 0; mf < 4; ++mf)
#pragma unroll
                for (int nf = 0; nf < 4; ++nf)
                    acc[mf][nf] = __builtin_amdgcn_mfma_f32_16x16x32_bf16(
                        af[mf], bfr[nf], acc[mf][nf], 0, 0, 0);
        }
    }

#pragma unroll
    for (int mf = 0; mf < 4; ++mf) {
#pragma unroll
        for (int reg = 0; reg < 4; ++reg) {
            int co = rowBase + mw * 64 + mf * 16 + lk * 4 + reg;
            float sc = scale[co], sh = shift[co];
#pragma unroll
            for (int nf = 0; nf < 4; ++nf) {
                int col = colBase + nw * 64 + nf * 16 + lr;
                float y = acc[mf][nf][reg] * sc + sh;
                if (silu) y = y / (1.f + expf(-y));
                Cn[(long)co * 4096 + col] = y;
            }
        }
    }
}

// ---------------- prep_in2t (merged roots): in2t + weight transposes + rings + bn ----------------
__global__ __launch_bounds__(256) void prep_in2t_kernel(
    const float* __restrict__ input2, u16* __restrict__ in2T,
    const float* __restrict__ w_conv, const float* __restrict__ w_up,
    const float* __restrict__ w_enc, const float* __restrict__ w_down,
    const float* __restrict__ bn_conv, const float* __restrict__ b_up,
    const float* __restrict__ w_l2,
    u16* __restrict__ wT, u16* __restrict__ wupT, u16* __restrict__ wencT,
    u16* __restrict__ wdT, u16* __restrict__ ftb, u16* __restrict__ ktT,
    float* __restrict__ bnp, float* __restrict__ wl2T)
{
    constexpr int CP = 264;
    __shared__ u16 lds[64 * CP];        // 33.8 KB, used by in2t branch only
    const int bid = blockIdx.x;
    const int tid = threadIdx.x;
    if (bid < 256) {                    // ---- in2t: transpose-cast input2 ----
        const int n = bid >> 5;
        const int c0 = ((bid >> 4) & 1) << 8;
        const int p0 = (bid & 15) * 64;
        {
            const int px = tid & 63;
            const float* src = input2 + (long)n * 512 * 1024 + (long)c0 * 1024 + p0 + px;
            for (int ci = tid >> 6; ci < 256; ci += 4)
                lds[px * CP + ci] = f2bf(src[(long)ci * 1024]);
        }
        __syncthreads();
        const int px = tid >> 2;
        const int qd = tid & 3;
        u16* drow = in2T + ((long)n * 1024 + p0 + px) * 512 + c0;
        const u16* lrow = lds + px * CP;
#pragma unroll
        for (int j = 0; j < 8; ++j) {
            int off = j * 32 + qd * 8;
            *(uint4*)(drow + off) = *(const uint4*)(lrow + off);
        }
        return;
    }
    if (bid < 2560) {                   // ---- weight transposes ----
        int gid = (bid - 256) * 256 + tid;
        if (gid < 589824) {             // wT[t][co][ci] = w_conv[co][ci][t]
            int t = gid >> 16;
            int co = (gid >> 8) & 255;
            int ci = gid & 255;
            wT[gid] = f2bf(w_conv[(co * 256 + ci) * 9 + t]);
        }
        if (gid < 131072) wupT[gid] = f2bf(w_up[gid]);
        if (gid < 73728) {              // wencT[t][co<64][ci] (zeros co>=36)
            int t = gid >> 13;
            int co = (gid >> 7) & 63;
            int ci = gid & 127;
            wencT[gid] = (co < 36) ? f2bf(w_enc[(co * 128 + ci) * 9 + t]) : (u16)0;
        }
        if (gid < 65536) wdT[gid] = f2bf(w_down[gid]);
        return;
    }
    if (bid < 2886) {                   // ---- border rings ----
        int gid = (bid - 2560) * 256 + tid;
        if (gid < 8 * 260 * 32) {       // fusedT ring
            int n = gid / (260 * 32);
            int rem = gid - n * (260 * 32);
            int r = rem >> 5;
            int i = rem & 31;
            int h, w;
            if (r < 66)       { h = 0;  w = r; }
            else if (r < 132) { h = 65; w = r - 66; }
            else { int j = r - 132; h = 1 + (j >> 1); w = (j & 1) * 65; }
            long prow = (long)h * 66 + w;
            uint4* dst = (uint4*)(ftb + (long)n * 4356 * 256 + prow * 256) + i;
            *dst = make_uint4(0, 0, 0, 0);
            return;
        }
        int g2 = gid - 8 * 260 * 32;    // ktT ring
        if (g2 >= 8 * 132 * 16) return;
        int n = g2 / (132 * 16);
        int rem = g2 - n * (132 * 16);
        int r = rem >> 4;
        int i = rem & 15;
        int h, w;
        if (r < 34)      { h = 0;  w = r; }
        else if (r < 68) { h = 33; w = r - 34; }
        else { int j = r - 68; h = 1 + (j >> 1); w = (j & 1) * 33; }
        long prow = (long)h * 34 + w;
        uint4* dst = (uint4*)(ktT + (long)n * 1156 * 128 + prow * 128) + i;
        *dst = make_uint4(0, 0, 0, 0);
        return;
    }
    {                                   // ---- bn block (bid == 2886) ----
        int i = tid;                    // 256
        float g = bn_conv[i], b = bn_conv[256 + i], m = bn_conv[512 + i], v = bn_conv[768 + i];
        float sc = g * rsqrtf(v + EPS);
        bnp[i] = sc;
        bnp[256 + i] = b - m * sc;
        bnp[768 + i] = b_up[i];
        if (i < 8) {                    // c2[j] = w_l2[j] . b_up
            float s = 0.f;
            for (int co = 0; co < 256; ++co) s += w_l2[i * 256 + co] * b_up[co];
            bnp[512 + i] = s;
        }
#pragma unroll
        for (int j = 0; j < 8; ++j)     // wl2T[co][j]
            wl2T[i * 8 + j] = w_l2[j * 256 + i];
    }
}

extern "C" void kernel_launch(void* const* d_in, const int* in_sizes, int n_in,
                              void* d_out, int out_size, void* d_ws, size_t ws_size,
                              hipStream_t stream)
{
    const float* input1 = (const float*)d_in[0];
    const float* input2 = (const float*)d_in[1];
    const float* w_down = (const float*)d_in[2];
    const float* b_down = (const float*)d_in[3];
    const float* w_enc  = (const float*)d_in[4];
    const float* b_enc  = (const float*)d_in[5];
    const float* w_up   = (const float*)d_in[6];
    const float* b_up   = (const float*)d_in[7];
    const float* w_l1   = (const float*)d_in[8];
    const float* bn_l1  = (const float*)d_in[9];
    const float* w_l2   = (const float*)d_in[10];
    const float* bn_l2  = (const float*)d_in[11];
    const float* w_wl   = (const float*)d_in[12];
    const float* b_wl   = (const float*)d_in[13];
    const float* w_conv = (const float*)d_in[14];
    const float* bn_conv= (const float*)d_in[15];
    float* out = (float*)d_out;

    // workspace layout (float units). ~38.5 MB total.
    float* ws     = (float*)d_ws;
    float* ktTf   = ws;                      //   591,872 f : ktT bf16 [n][1156][128]
    float* wencTf = ktTf + 591872;           //    36,864 f
    float* maskb  = wencTf + 36864;          //   294,912 f
    float* in2Tf  = maskb + 294912;          // 2,097,152 f : in2T bf16 [n][1024][512]
    float* zbfTf  = in2Tf + 2097152;         // 1,048,576 f : zbfT bf16 [n][1024][256]
    float* zwT    = zbfTf + 1048576;         //    65,536 f : [n][1024][8] fp32
    float* ftbf   = zwT + 65536;             // 4,460,544 f : fusedT bf16 [n][4356][256]
    float* wTf    = ftbf + 4460544;          //   294,912 f
    float* wupTf  = wTf + 294912;            //    65,536 f
    float* wdTf   = wupTf + 65536;           //    32,768 f
    float* wl2T   = wdTf + 32768;            //     2,048 f
    float* bnp    = wl2T + 2048;             //     1,024 f
    float* v1buf  = bnp + 1024;              //   262,144 f : [n][4096][8] fp32
    u16* ktT      = (u16*)ktTf;
    u16* wencT    = (u16*)wencTf;
    u16* in2T     = (u16*)in2Tf;
    u16* zbfT     = (u16*)zbfTf;
    u16* ftb      = (u16*)ftbf;
    u16* wT       = (u16*)wTf;
    u16* wupT     = (u16*)wupTf;
    u16* wdT      = (u16*)wdTf;

    // merged roots: in2t (first 256 blocks) + prep transposes + rings + bn
    prep_in2t_kernel<<<dim3(2887), 256, 0, stream>>>(
        input2, in2T, w_conv, w_up, w_enc, w_down, bn_conv, b_up, w_l2,
        wT, wupT, wencT, wdT, ftb, ktT, bnp, wl2T);

    // merged lowres GEMM (bid<192) + hoisted v1 pass (bid>=192, idle-CU fill)
    lowres_gemm_kernel<<<dim3(192 + 1024), 256, 0, stream>>>(
        wupT, wdT, in2T, b_down, input1, w_l1, zbfT, ktT, v1buf);

    // merged enc-softmax (bid<512) + zw (bid>=512)
    encsm_zw_kernel<<<dim3(512 + 8192), 64, 0, stream>>>(
        wencT, ktT, b_enc, zbfT, wl2T, maskb, zwT);

    // merged level-attention + CARAFE + blend -> fusedT (wave-parallel lw0)
    carafe_fuse_blend_kernel<<<dim3(128, 8), 256, 0, stream>>>(
        input1, zbfT, zwT, maskb, bnp, v1buf, bn_l1, bn_l2, w_wl, b_wl, ftb);

    // K7: final conv + BN + SiLU (round-11 schedule)
    gemm_m97_kernel<256, 9, true><<<dim3(32, 2, 8), 256, 0, stream>>>(
        wT, ftb, bnp, bnp + 256, out, 4356L * 256, 256L * 4096, 1);
}

// Round 31
// 118.062 us; speedup vs baseline: 1.0116x; 1.0116x over previous
//
#include <hip/hip_runtime.h>
#include <math.h>

// ASFF_2: N=8, C1=256, C2=512, H=64, W=64, low-res 32x32.
// CARAFE-commutation: u = CARAFE(z)+b_up with z = w_up@in2 (low-res GEMM);
// v2 = CARAFE(zw)+c2 with zw = w_l2@z, c2 = w_l2@b_up.
//  prep_in2t (merged ROOTS): in2t + weight transposes + rings + bn
//  lowres_gemm (merged + v1 hoist): bid<192 -> GEMM (zbfT / ktT);
//      bid>=192 -> v1buf = reduce(w_l1 @ input1)  [fills the 64 idle CUs]
//  encsm_zw (merged dispatch): enc MFMA+softmax -> maskb ; zw = w_l2@z
//  carafe_fuse_blend: lw0 on tid<32 (round-30's wave-parallel rewrite
//      REGRESSED +1.2us — lw0 was already hidden; reverted) ; pass2 blend
//  K7: m97 GEMM, round-11 pre-barrier triple-buffer schedule (53.1us ceiling).

#define EPS 1e-5f
typedef unsigned short u16;
typedef __attribute__((ext_vector_type(8))) __bf16 bf16x8;
typedef __attribute__((ext_vector_type(4))) float f32x4;

#define VMCNT(N) asm volatile("s_waitcnt vmcnt(" #N ")" ::: "memory")

__device__ inline u16 f2bf(float x) {
    union { float f; unsigned u; } v; v.f = x;
    unsigned r = v.u + 0x7FFF + ((v.u >> 16) & 1);
    return (u16)(r >> 16);
}
__device__ inline float bf2f(u16 x) {
    union { unsigned u; float f; } v; v.u = (unsigned)x << 16; return v.f;
}

// ---------------- staging macros ----------------
#define STAGE_A(dstp, t, kx)                                                         \
    {                                                                                \
        const u16* Abase = A + ((long)(t) * 256 + rowBase) * KCC + (kx) * 32;        \
        _Pragma("unroll")                                                            \
        for (int ii = 0; ii < 2; ++ii) {                                             \
            int f = ii * 256 + tid;                                                  \
            int r = f >> 2, uu = f & 3;                                              \
            __builtin_amdgcn_global_load_lds(                                        \
                (const __attribute__((address_space(1))) void*)                      \
                    (Abase + (long)r * KCC + ((uu ^ ((r >> 1) & 3)) << 3)),          \
                (__attribute__((address_space(3))) void*)((dstp) + f * 8),           \
                16, 0, 0);                                                           \
        }                                                                            \
    }

#define STAGE_B(dstp, kx)                                                            \
    {                                                                                \
        const u16* Bbase = Bn + (long)g0 * KCC + (kx) * 32;                          \
        for (int f = tid; f < BUNITS; f += 256) {                                    \
            int r = f >> 2, uu = f & 3;                                              \
            __builtin_amdgcn_global_load_lds(                                        \
                (const __attribute__((address_space(1))) void*)                      \
                    (Bbase + (long)r * KCC + ((uu ^ ((r >> 1) & 3)) << 3)),          \
                (__attribute__((address_space(3))) void*)((dstp) + f * 8),           \
                16, 0, 0);                                                           \
        }                                                                            \
    }

// ---------------- lowres_gemm (merged zgemm + down_mfma + hoisted v1 pass) ----------------
// Flattened grid: bid < 192 -> GEMM (x=bid&7, ybr=(bid>>3)%3, n=bid/24);
// bid >= 192 -> v1 blocks (1024): v1buf[n][4096][8] = reduce(w_l1 @ input1).
__global__ __launch_bounds__(256, 2) void lowres_gemm_kernel(
    const u16* __restrict__ Aup,    // wupT [256][512]
    const u16* __restrict__ Adn,    // wdT  [128][512]
    const u16* __restrict__ B,      // in2T [n][1024][512]
    const float* __restrict__ bias, // b_down
    const float* __restrict__ i1g, const float* __restrict__ w_l1,
    u16* __restrict__ Z,            // zbfT [n][1024][256]
    u16* __restrict__ ktT,          // [n][1156][128] padded
    float* __restrict__ v1buf)      // [n][4096][8] fp32
{
    constexpr int KCC = 512;
    constexpr int BUNITS = 512;
    __shared__ __align__(16) u16 lsA[3][128 * 32];
    __shared__ __align__(16) u16 lsB[3][128 * 32];
    const int bid0 = blockIdx.x;
    const int tid = threadIdx.x;

    if (bid0 >= 192) {                  // ---- v1 branch (fills idle CUs) ----
        float* red = (float*)lsA;       // 8KB scratch in the 24KB lsA
        const int vb = bid0 - 192;      // 0..1023
        const int n = vb >> 7;
        const int hw = vb & 127;
        const int h = hw >> 1;
        const int w0 = (hw & 1) << 5;
        const int w = tid & 31;
        const int chunk = tid >> 5;
        const float* i1 = i1g + (long)n * 256 * 4096 + (h << 6) + w0 + w;
        float s1[8] = {};
        for (int i = 0; i < 32; ++i) {
            const int ci = chunk * 32 + i;
            float x1 = i1[(long)ci * 4096];
#pragma unroll
            for (int j = 0; j < 8; ++j) s1[j] += w_l1[j * 256 + ci] * x1;
        }
#pragma unroll
        for (int j = 0; j < 8; ++j) red[(chunk * 32 + w) * 8 + j] = s1[j];
        __syncthreads();
        const int px = tid >> 3, j = tid & 7;
        float s = 0.f;
#pragma unroll
        for (int o = 0; o < 8; ++o) s += red[(o * 32 + px) * 8 + j];
        v1buf[((long)n * 4096 + (h << 6) + w0 + px) * 8 + j] = s;
        return;
    }

    // ---- GEMM branch ----
    const int xb = bid0 & 7;
    const int ybr = (bid0 >> 3) % 3;
    const int n = bid0 / 24;
    const u16* Bn = B + (long)n * 1024 * 512;
    const int lane = tid & 63;
    const int wid = tid >> 6;
    const int mw = wid >> 1, nw = wid & 1;
    const int lr = lane & 15, lk = lane >> 4;
    const u16* A = (ybr < 2) ? Aup : Adn;
    const int rowBase = (ybr < 2) ? ybr * 128 : 0;
    const int colBase = xb * 128;
    const int g0 = colBase;

    STAGE_A(lsA[0], 0, 0); STAGE_B(lsB[0], 0);
    STAGE_A(lsA[1], 0, 1); STAGE_B(lsB[1], 1);

    const int aswz = (lk ^ ((lr >> 1) & 3)) << 3;
    int aoff[4];
#pragma unroll
    for (int mf = 0; mf < 4; ++mf)
        aoff[mf] = (mw * 64 + mf * 16 + lr) * 32 + aswz;

    f32x4 acc[4][4] = {};
    for (int kx = 0; kx < 16; ++kx) {
        if (kx == 15) { VMCNT(0); } else { VMCNT(4); }
        __builtin_amdgcn_s_barrier();
        asm volatile("" ::: "memory");
        if (kx + 2 < 16) {
            STAGE_A(lsA[(kx + 2) % 3], 0, kx + 2);
            STAGE_B(lsB[(kx + 2) % 3], kx + 2);
        }
        const u16* la = lsA[kx % 3];
        const u16* lb = lsB[kx % 3];
        bf16x8 af[4], bfr[4];
#pragma unroll
        for (int mf = 0; mf < 4; ++mf)
            af[mf] = *(const bf16x8*)(la + aoff[mf]);
        const int rb = nw * 64 + lr;
        const int bswz = (lk ^ ((rb >> 1) & 3)) << 3;
#pragma unroll
        for (int nf = 0; nf < 4; ++nf)
            bfr[nf] = *(const bf16x8*)(lb + (rb + nf * 16) * 32 + bswz);
#pragma unroll
        for (int mf = 0; mf < 4; ++mf)
#pragma unroll
            for (int nf = 0; nf < 4; ++nf)
                acc[mf][nf] = __builtin_amdgcn_mfma_f32_16x16x32_bf16(
                    af[mf], bfr[nf], acc[mf][nf], 0, 0, 0);
    }

    if (ybr < 2) {
        u16* Zn = Z + (long)n * 1024 * 256;
#pragma unroll
        for (int mf = 0; mf < 4; ++mf) {
            const int co0 = rowBase + mw * 64 + mf * 16 + lk * 4;
#pragma unroll
            for (int nf = 0; nf < 4; ++nf) {
                const int col = colBase + nw * 64 + nf * 16 + lr;
                unsigned lo = (unsigned)f2bf(acc[mf][nf][0]) |
                              ((unsigned)f2bf(acc[mf][nf][1]) << 16);
                unsigned hi = (unsigned)f2bf(acc[mf][nf][2]) |
                              ((unsigned)f2bf(acc[mf][nf][3]) << 16);
                *(uint2*)(Zn + (long)col * 256 + co0) = make_uint2(lo, hi);
            }
        }
    } else {
        u16* Kn = ktT + (long)n * 1156 * 128;
#pragma unroll
        for (int mf = 0; mf < 4; ++mf) {
            const int co0 = mw * 64 + mf * 16 + lk * 4;     // 0..124
            float b0 = bias[co0], b1 = bias[co0 + 1], b2 = bias[co0 + 2], b3 = bias[co0 + 3];
#pragma unroll
            for (int nf = 0; nf < 4; ++nf) {
                const int col = colBase + nw * 64 + nf * 16 + lr;   // 0..1023
                const int pr = ((col >> 5) + 1) * 34 + (col & 31) + 1;
                unsigned lo = (unsigned)f2bf(acc[mf][nf][0] + b0) |
                              ((unsigned)f2bf(acc[mf][nf][1] + b1) << 16);
                unsigned hi = (unsigned)f2bf(acc[mf][nf][2] + b2) |
                              ((unsigned)f2bf(acc[mf][nf][3] + b3) << 16);
                *(uint2*)(Kn + (long)pr * 128 + co0) = make_uint2(lo, hi);
            }
        }
    }
}

// ---------------- encsm_zw: merged enc-softmax (bid<512) + zw (bid>=512) ----------------
__global__ __launch_bounds__(64) void encsm_zw_kernel(
    const u16* __restrict__ A, const u16* __restrict__ B,   // wencT, ktT
    const float* __restrict__ bias,                         // b_enc
    const u16* __restrict__ zbfT, const float* __restrict__ wl2T,
    float* __restrict__ mask, float* __restrict__ zwT)
{
    const int bid = blockIdx.x;
    const int lane = threadIdx.x;
    if (bid < 512) {
        const int n = bid >> 6;
        const int lr = lane & 15, lk = lane >> 4;
        const int p = (bid & 63) * 16 + lr;
        const int pr = ((p >> 5) + 1) * 34 + (p & 31) + 1;
        const u16* Bn = B + (long)n * 1156 * 128;
        const int bOff = pr * 128 + lk * 8;
        f32x4 acc[3] = {};
        for (int t = 0; t < 9; ++t) {
            const u16* At = A + t * 8192;
            const int btap = ((t / 3 - 1) * 34 + (t % 3 - 1)) * 128;
#pragma unroll
            for (int k0 = 0; k0 < 128; k0 += 32) {
                bf16x8 bf = *(const bf16x8*)(Bn + bOff + btap + k0);
#pragma unroll
                for (int mf = 0; mf < 3; ++mf) {
                    bf16x8 af = *(const bf16x8*)(At + (mf * 16 + lr) * 128 + lk * 8 + k0);
                    acc[mf] = __builtin_amdgcn_mfma_f32_16x16x32_bf16(af, bf, acc[mf], 0, 0, 0);
                }
            }
        }
        float* mp = mask + ((long)n * 1024 + p) * 36;
#pragma unroll
        for (int q = 0; q < 4; ++q) {
            float v0 = acc[0][q] + bias[lk * 4 + q];            // k = lk
            float v1 = acc[1][q] + bias[16 + lk * 4 + q];       // k = 4 + lk
            float v2 = (lk == 0) ? (acc[2][q] + bias[32 + q]) : -1e30f;   // k = 8
            float m = fmaxf(fmaxf(v0, v1), v2);
            m = fmaxf(m, __shfl_xor(m, 16, 64));
            m = fmaxf(m, __shfl_xor(m, 32, 64));
            float e0 = expf(v0 - m);
            float e1 = expf(v1 - m);
            float e2 = (lk == 0) ? expf(v2 - m) : 0.f;
            float s = e0 + e1 + e2;
            s += __shfl_xor(s, 16, 64);
            s += __shfl_xor(s, 32, 64);
            float inv = 1.f / s;
            mp[lk * 4 + q] = e0 * inv;
            mp[16 + lk * 4 + q] = e1 * inv;
            if (lk == 0) mp[32 + q] = e2 * inv;
        }
    } else {
        const int Q = bid - 512;            // 0..8191
        const int ci0 = lane * 4;
        uint2 v = *(const uint2*)(zbfT + (long)Q * 256 + ci0);
        float c[4] = { bf2f((u16)(v.x & 0xffff)), bf2f((u16)(v.x >> 16)),
                       bf2f((u16)(v.y & 0xffff)), bf2f((u16)(v.y >> 16)) };
        float s[8] = {};
#pragma unroll
        for (int t = 0; t < 4; ++t) {
            const float* wr = wl2T + (ci0 + t) * 8;
            float4 wa = *(const float4*)wr;
            float4 wb = *(const float4*)(wr + 4);
            s[0] += wa.x * c[t]; s[1] += wa.y * c[t]; s[2] += wa.z * c[t]; s[3] += wa.w * c[t];
            s[4] += wb.x * c[t]; s[5] += wb.y * c[t]; s[6] += wb.z * c[t]; s[7] += wb.w * c[t];
        }
#pragma unroll
        for (int off = 1; off < 64; off <<= 1)
#pragma unroll
            for (int j = 0; j < 8; ++j)
                s[j] += __shfl_xor(s[j], off, 64);
        if (lane == 0) {
            float* o = zwT + (long)Q * 8;
            *(float4*)o = make_float4(s[0], s[1], s[2], s[3]);
            *(float4*)(o + 4) = make_float4(s[4], s[5], s[6], s[7]);
        }
    }
}

// ---------------- carafe_fuse_blend: lw0 from hoisted v1buf ; pass2 CARAFE+blend ----------------
__global__ __launch_bounds__(256) void carafe_fuse_blend_kernel(
    const float* __restrict__ i1g, const u16* __restrict__ zbfT,
    const float* __restrict__ zwT, const float* __restrict__ maskb,
    const float* __restrict__ bnp,          // 512..519 c2, 768.. b_up
    const float* __restrict__ v1buf, const float* __restrict__ bn_l1,
    const float* __restrict__ bn_l2, const float* __restrict__ w_wl,
    const float* __restrict__ b_wl, u16* __restrict__ dst)
{
    __shared__ float lw0s[32];
    __shared__ __align__(16) u16 lds2[32 * 264];    // 16.5 KB
    const int n = blockIdx.y;
    const int h = blockIdx.x >> 1;
    const int w0 = (blockIdx.x & 1) << 5;
    const int hq = h >> 1;
    const int tid = threadIdx.x;
    const int w = tid & 31;
    const int chunk = tid >> 5;

    if (tid < 32) {     // lw0 per pixel (v1 from v1buf; mask/zw from L2)
        const int wp = w0 + tid;
        const int wq = wp >> 1;
        const int q = ((h & 1) << 1) | (wp & 1);
        const float* mrow = maskb + ((long)n * 1024 + hq * 32 + wq) * 36;
        float v[16];
        {
            const float* vp = v1buf + ((long)n * 4096 + (h << 6) + wp) * 8;
            float4 va = *(const float4*)vp;
            float4 vb = *(const float4*)(vp + 4);
            v[0] = va.x; v[1] = va.y; v[2] = va.z; v[3] = va.w;
            v[4] = vb.x; v[5] = vb.y; v[6] = vb.z; v[7] = vb.w;
        }
#pragma unroll
        for (int j = 0; j < 8; ++j) v[8 + j] = bnp[512 + j];   // c2
#pragma unroll
        for (int k = 0; k < 9; ++k) {
            int dh = k / 3 - 1, dw = k - (k / 3) * 3 - 1;
            int gr = hq + dh, gc = wq + dw;
            bool ok = (gr >= 0 && gr < 32 && gc >= 0 && gc < 32);
            float mk = ok ? mrow[k * 4 + q] : 0.f;
            const float* zp = zwT + ((long)n * 1024 +
                                     (ok ? gr * 32 + gc : hq * 32 + wq)) * 8;
            float4 za = *(const float4*)zp;
            float4 zb = *(const float4*)(zp + 4);
            v[8]  += mk * za.x; v[9]  += mk * za.y; v[10] += mk * za.z; v[11] += mk * za.w;
            v[12] += mk * zb.x; v[13] += mk * zb.y; v[14] += mk * zb.z; v[15] += mk * zb.w;
        }
        float z0 = b_wl[0], z1 = b_wl[1];
#pragma unroll
        for (int j = 0; j < 8; ++j) {
            float g = bn_l1[j], b = bn_l1[8 + j], m = bn_l1[16 + j], va = bn_l1[24 + j];
            float y = (v[j] - m) * (g * rsqrtf(va + EPS)) + b;
            float sv = y / (1.f + expf(-y));
            z0 += w_wl[j] * sv;
            z1 += w_wl[16 + j] * sv;
            g = bn_l2[j]; b = bn_l2[8 + j]; m = bn_l2[16 + j]; va = bn_l2[24 + j];
            y = (v[8 + j] - m) * (g * rsqrtf(va + EPS)) + b;
            sv = y / (1.f + expf(-y));
            z0 += w_wl[8 + j] * sv;
            z1 += w_wl[24 + j] * sv;
        }
        lw0s[tid] = 1.f / (1.f + expf(z1 - z0));
    }
    __syncthreads();
    {   // pass2: u = CARAFE(z from L2)+b_up ; blend (i1 L3-hot) ; bf16 into lds2
        const float lw = lw0s[w], lw1 = 1.f - lw;
        const int wp = w0 + w;
        const int wq = wp >> 1;
        const int q = ((h & 1) << 1) | (wp & 1);
        const float* i1 = i1g + (long)n * 256 * 4096 + (h << 6) + w0 + w;
        const float* mrow = maskb + ((long)n * 1024 + hq * 32 + wq) * 36;
        float m9[9];
        const u16* zp[9];
#pragma unroll
        for (int k = 0; k < 9; ++k) {
            int dh = k / 3 - 1, dw = k - (k / 3) * 3 - 1;
            int gr = hq + dh, gc = wq + dw;
            bool ok = (gr >= 0 && gr < 32 && gc >= 0 && gc < 32);
            m9[k] = ok ? mrow[k * 4 + q] : 0.f;
            zp[k] = zbfT + ((long)n * 1024 +
                            (ok ? gr * 32 + gc : hq * 32 + wq)) * 256;
        }
        for (int ci = chunk * 32; ci < chunk * 32 + 32; ci += 8) {
            float uu[8];
            {
                float4 ba = *(const float4*)(bnp + 768 + ci);
                float4 bb = *(const float4*)(bnp + 768 + ci + 4);
                uu[0] = ba.x; uu[1] = ba.y; uu[2] = ba.z; uu[3] = ba.w;
                uu[4] = bb.x; uu[5] = bb.y; uu[6] = bb.z; uu[7] = bb.w;
            }
#pragma unroll
            for (int k = 0; k < 9; ++k) {
                uint4 vz = *(const uint4*)(zp[k] + ci);
                float mk = m9[k];
                uu[0] += mk * bf2f((u16)(vz.x & 0xffff));
                uu[1] += mk * bf2f((u16)(vz.x >> 16));
                uu[2] += mk * bf2f((u16)(vz.y & 0xffff));
                uu[3] += mk * bf2f((u16)(vz.y >> 16));
                uu[4] += mk * bf2f((u16)(vz.z & 0xffff));
                uu[5] += mk * bf2f((u16)(vz.z >> 16));
                uu[6] += mk * bf2f((u16)(vz.w & 0xffff));
                uu[7] += mk * bf2f((u16)(vz.w >> 16));
            }
            unsigned o0 = (unsigned)f2bf(i1[(long)ci * 4096] * lw + uu[0] * lw1)
                        | ((unsigned)f2bf(i1[(long)(ci + 1) * 4096] * lw + uu[1] * lw1) << 16);
            unsigned o1 = (unsigned)f2bf(i1[(long)(ci + 2) * 4096] * lw + uu[2] * lw1)
                        | ((unsigned)f2bf(i1[(long)(ci + 3) * 4096] * lw + uu[3] * lw1) << 16);
            unsigned o2 = (unsigned)f2bf(i1[(long)(ci + 4) * 4096] * lw + uu[4] * lw1)
                        | ((unsigned)f2bf(i1[(long)(ci + 5) * 4096] * lw + uu[5] * lw1) << 16);
            unsigned o3 = (unsigned)f2bf(i1[(long)(ci + 6) * 4096] * lw + uu[6] * lw1)
                        | ((unsigned)f2bf(i1[(long)(ci + 7) * 4096] * lw + uu[7] * lw1) << 16);
            *(uint4*)(lds2 + w * 264 + ci) = make_uint4(o0, o1, o2, o3);
        }
    }
    __syncthreads();
    {   // transposed padded write
        const int px = tid >> 3, qd = tid & 7;
        const int pg = (h << 6) + w0 + px;
        long prow = (long)((pg >> 6) + 1) * 66 + (pg & 63) + 1;
        u16* drow = dst + (long)n * 4356 * 256 + prow * 256;
        const u16* lrow = lds2 + px * 264;
#pragma unroll
        for (int j = 0; j < 16; ++j) {
            int off = j * 16 + qd * 2;
            *(unsigned*)(drow + off) = *(const unsigned*)(lrow + off);
        }
    }
}

// ---------------- K7: m97 GEMM — round-11 pre-barrier triple-buffer (measured 53.1us) ----------------
template<int KCC, int NT, bool PADDED>
__global__ __launch_bounds__(256, 2) void gemm_m97_kernel(
    const u16* __restrict__ A,      // [NT][256][KCC] bf16
    const u16* __restrict__ B,      // per image [rows][KCC] bf16
    const float* __restrict__ scale, const float* __restrict__ shift,
    float* __restrict__ C, long strideB, long strideC, int silu)
{
    constexpr int RROWS = PADDED ? 264 : 128;
    constexpr int BUNITS = RROWS * 4;
    constexpr int NKX = KCC / 32;
    constexpr int MINB = BUNITS / 256;      // 4 (K7)
    __shared__ __align__(16) u16 lsA[3][128 * 32];
    __shared__ __align__(16) u16 lsB[3][RROWS * 32];
    const int n = blockIdx.z;
    const u16* Bn = B + (long)n * strideB;
    float* Cn = C + (long)n * strideC;
    const int tid = threadIdx.x;
    const int lane = tid & 63;
    const int wid = tid >> 6;
    const int mw = wid >> 1, nw = wid & 1;
    const int lr = lane & 15, lk = lane >> 4;
    const int rowBase = blockIdx.y * 128;
    const int colBase = blockIdx.x * 128;
    const int g0 = PADDED ? (colBase >> 6) * 66 : colBase;

    STAGE_B(lsB[0], 0);
    STAGE_A(lsA[0], 0, 0);

    const int aswz = (lk ^ ((lr >> 1) & 3)) << 3;
    int aoff[4];
#pragma unroll
    for (int mf = 0; mf < 4; ++mf)
        aoff[mf] = (mw * 64 + mf * 16 + lr) * 32 + aswz;

    f32x4 acc[4][4] = {};
    for (int kx = 0; kx < NKX; ++kx) {
        const u16* lb = lsB[kx % 3];
#pragma unroll
        for (int t = 0; t < NT; ++t) {
            const int s = kx * NT + t;
            const bool lastS = (kx == NKX - 1) && (t == NT - 1);
            const bool stgB = (t == 0) && (kx + 1 < NKX);
            if (stgB) STAGE_B(lsB[(kx + 1) % 3], kx + 1);
            if (!lastS) {
                const int t1 = (t + 1 == NT) ? 0 : t + 1;
                const int kx1 = (t + 1 == NT) ? kx + 1 : kx;
                STAGE_A(lsA[(s + 1) % 3], t1, kx1);
            }
            // counted wait: N = loads issued THIS phase (min over threads)
            if (lastS) { VMCNT(0); }
            else if (stgB) { if constexpr (MINB == 2) VMCNT(4); else VMCNT(6); }
            else { VMCNT(2); }
            __builtin_amdgcn_s_barrier();
            asm volatile("" ::: "memory");

            const u16* la = lsA[s % 3];
            bf16x8 af[4], bfr[4];
#pragma unroll
            for (int mf = 0; mf < 4; ++mf)
                af[mf] = *(const bf16x8*)(la + aoff[mf]);
            int rb;
            if (PADDED) {
                int dh = t / 3 - 1, dw = t - (t / 3) * 3 - 1;
                rb = (nw + dh + 1) * 66 + dw + 1 + lr;
            } else {
                rb = nw * 64 + lr;
            }
            const int bswz = (lk ^ ((rb >> 1) & 3)) << 3;
#pragma unroll
            for (int nf = 0; nf < 4; ++nf)
                bfr[nf] = *(const bf16x8*)(lb + (rb + nf * 16) * 32 + bswz);
#pragma unroll
            for (int mf = 0; mf < 4; ++mf)
#pragma unroll
                for (int nf = 0; nf < 4; ++nf)
                    acc[mf][nf] = __builtin_amdgcn_mfma_f32_16x16x32_bf16(
                        af[mf], bfr[nf], acc[mf][nf], 0, 0, 0);
        }
    }

#pragma unroll
    for (int mf = 0; mf < 4; ++mf) {
#pragma unroll
        for (int reg = 0; reg < 4; ++reg) {
            int co = rowBase + mw * 64 + mf * 16 + lk * 4 + reg;
            float sc = scale[co], sh = shift[co];
#pragma unroll
            for (int nf = 0; nf < 4; ++nf) {
                int col = colBase + nw * 64 + nf * 16 + lr;
                float y = acc[mf][nf][reg] * sc + sh;
                if (silu) y = y / (1.f + expf(-y));
                Cn[(long)co * 4096 + col] = y;
            }
        }
    }
}

// ---------------- prep_in2t (merged roots): in2t + weight transposes + rings + bn ----------------
__global__ __launch_bounds__(256) void prep_in2t_kernel(
    const float* __restrict__ input2, u16* __restrict__ in2T,
    const float* __restrict__ w_conv, const float* __restrict__ w_up,
    const float* __restrict__ w_enc, const float* __restrict__ w_down,
    const float* __restrict__ bn_conv, const float* __restrict__ b_up,
    const float* __restrict__ w_l2,
    u16* __restrict__ wT, u16* __restrict__ wupT, u16* __restrict__ wencT,
    u16* __restrict__ wdT, u16* __restrict__ ftb, u16* __restrict__ ktT,
    float* __restrict__ bnp, float* __restrict__ wl2T)
{
    constexpr int CP = 264;
    __shared__ u16 lds[64 * CP];        // 33.8 KB, used by in2t branch only
    const int bid = blockIdx.x;
    const int tid = threadIdx.x;
    if (bid < 256) {                    // ---- in2t: transpose-cast input2 ----
        const int n = bid >> 5;
        const int c0 = ((bid >> 4) & 1) << 8;
        const int p0 = (bid & 15) * 64;
        {
            const int px = tid & 63;
            const float* src = input2 + (long)n * 512 * 1024 + (long)c0 * 1024 + p0 + px;
            for (int ci = tid >> 6; ci < 256; ci += 4)
                lds[px * CP + ci] = f2bf(src[(long)ci * 1024]);
        }
        __syncthreads();
        const int px = tid >> 2;
        const int qd = tid & 3;
        u16* drow = in2T + ((long)n * 1024 + p0 + px) * 512 + c0;
        const u16* lrow = lds + px * CP;
#pragma unroll
        for (int j = 0; j < 8; ++j) {
            int off = j * 32 + qd * 8;
            *(uint4*)(drow + off) = *(const uint4*)(lrow + off);
        }
        return;
    }
    if (bid < 2560) {                   // ---- weight transposes ----
        int gid = (bid - 256) * 256 + tid;
        if (gid < 589824) {             // wT[t][co][ci] = w_conv[co][ci][t]
            int t = gid >> 16;
            int co = (gid >> 8) & 255;
            int ci = gid & 255;
            wT[gid] = f2bf(w_conv[(co * 256 + ci) * 9 + t]);
        }
        if (gid < 131072) wupT[gid] = f2bf(w_up[gid]);
        if (gid < 73728) {              // wencT[t][co<64][ci] (zeros co>=36)
            int t = gid >> 13;
            int co = (gid >> 7) & 63;
            int ci = gid & 127;
            wencT[gid] = (co < 36) ? f2bf(w_enc[(co * 128 + ci) * 9 + t]) : (u16)0;
        }
        if (gid < 65536) wdT[gid] = f2bf(w_down[gid]);
        return;
    }
    if (bid < 2886) {                   // ---- border rings ----
        int gid = (bid - 2560) * 256 + tid;
        if (gid < 8 * 260 * 32) {       // fusedT ring
            int n = gid / (260 * 32);
            int rem = gid - n * (260 * 32);
            int r = rem >> 5;
            int i = rem & 31;
            int h, w;
            if (r < 66)       { h = 0;  w = r; }
            else if (r < 132) { h = 65; w = r - 66; }
            else { int j = r - 132; h = 1 + (j >> 1); w = (j & 1) * 65; }
            long prow = (long)h * 66 + w;
            uint4* dst = (uint4*)(ftb + (long)n * 4356 * 256 + prow * 256) + i;
            *dst = make_uint4(0, 0, 0, 0);
            return;
        }
        int g2 = gid - 8 * 260 * 32;    // ktT ring
        if (g2 >= 8 * 132 * 16) return;
        int n = g2 / (132 * 16);
        int rem = g2 - n * (132 * 16);
        int r = rem >> 4;
        int i = rem & 15;
        int h, w;
        if (r < 34)      { h = 0;  w = r; }
        else if (r < 68) { h = 33; w = r - 34; }
        else { int j = r - 68; h = 1 + (j >> 1); w = (j & 1) * 33; }
        long prow = (long)h * 34 + w;
        uint4* dst = (uint4*)(ktT + (long)n * 1156 * 128 + prow * 128) + i;
        *dst = make_uint4(0, 0, 0, 0);
        return;
    }
    {                                   // ---- bn block (bid == 2886) ----
        int i = tid;                    // 256
        float g = bn_conv[i], b = bn_conv[256 + i], m = bn_conv[512 + i], v = bn_conv[768 + i];
        float sc = g * rsqrtf(v + EPS);
        bnp[i] = sc;
        bnp[256 + i] = b - m * sc;
        bnp[768 + i] = b_up[i];
        if (i < 8) {                    // c2[j] = w_l2[j] . b_up
            float s = 0.f;
            for (int co = 0; co < 256; ++co) s += w_l2[i * 256 + co] * b_up[co];
            bnp[512 + i] = s;
        }
#pragma unroll
        for (int j = 0; j < 8; ++j)     // wl2T[co][j]
            wl2T[i * 8 + j] = w_l2[j * 256 + i];
    }
}

extern "C" void kernel_launch(void* const* d_in, const int* in_sizes, int n_in,
                              void* d_out, int out_size, void* d_ws, size_t ws_size,
                              hipStream_t stream)
{
    const float* input1 = (const float*)d_in[0];
    const float* input2 = (const float*)d_in[1];
    const float* w_down = (const float*)d_in[2];
    const float* b_down = (const float*)d_in[3];
    const float* w_enc  = (const float*)d_in[4];
    const float* b_enc  = (const float*)d_in[5];
    const float* w_up   = (const float*)d_in[6];
    const float* b_up   = (const float*)d_in[7];
    const float* w_l1   = (const float*)d_in[8];
    const float* bn_l1  = (const float*)d_in[9];
    const float* w_l2   = (const float*)d_in[10];
    const float* bn_l2  = (const float*)d_in[11];
    const float* w_wl   = (const float*)d_in[12];
    const float* b_wl   = (const float*)d_in[13];
    const float* w_conv = (const float*)d_in[14];
    const float* bn_conv= (const float*)d_in[15];
    float* out = (float*)d_out;

    // workspace layout (float units). ~38.5 MB total.
    float* ws     = (float*)d_ws;
    float* ktTf   = ws;                      //   591,872 f : ktT bf16 [n][1156][128]
    float* wencTf = ktTf + 591872;           //    36,864 f
    float* maskb  = wencTf + 36864;          //   294,912 f
    float* in2Tf  = maskb + 294912;          // 2,097,152 f : in2T bf16 [n][1024][512]
    float* zbfTf  = in2Tf + 2097152;         // 1,048,576 f : zbfT bf16 [n][1024][256]
    float* zwT    = zbfTf + 1048576;         //    65,536 f : [n][1024][8] fp32
    float* ftbf   = zwT + 65536;             // 4,460,544 f : fusedT bf16 [n][4356][256]
    float* wTf    = ftbf + 4460544;          //   294,912 f
    float* wupTf  = wTf + 294912;            //    65,536 f
    float* wdTf   = wupTf + 65536;           //    32,768 f
    float* wl2T   = wdTf + 32768;            //     2,048 f
    float* bnp    = wl2T + 2048;             //     1,024 f
    float* v1buf  = bnp + 1024;              //   262,144 f : [n][4096][8] fp32
    u16* ktT      = (u16*)ktTf;
    u16* wencT    = (u16*)wencTf;
    u16* in2T     = (u16*)in2Tf;
    u16* zbfT     = (u16*)zbfTf;
    u16* ftb      = (u16*)ftbf;
    u16* wT       = (u16*)wTf;
    u16* wupT     = (u16*)wupTf;
    u16* wdT      = (u16*)wdTf;

    // merged roots: in2t (first 256 blocks) + prep transposes + rings + bn
    prep_in2t_kernel<<<dim3(2887), 256, 0, stream>>>(
        input2, in2T, w_conv, w_up, w_enc, w_down, bn_conv, b_up, w_l2,
        wT, wupT, wencT, wdT, ftb, ktT, bnp, wl2T);

    // merged lowres GEMM (bid<192) + hoisted v1 pass (bid>=192, idle-CU fill)
    lowres_gemm_kernel<<<dim3(192 + 1024), 256, 0, stream>>>(
        wupT, wdT, in2T, b_down, input1, w_l1, zbfT, ktT, v1buf);

    // merged enc-softmax (bid<512) + zw (bid>=512)
    encsm_zw_kernel<<<dim3(512 + 8192), 64, 0, stream>>>(
        wencT, ktT, b_enc, zbfT, wl2T, maskb, zwT);

    // merged level-attention + CARAFE + blend -> fusedT (lw0 from v1buf)
    carafe_fuse_blend_kernel<<<dim3(128, 8), 256, 0, stream>>>(
        input1, zbfT, zwT, maskb, bnp, v1buf, bn_l1, bn_l2, w_wl, b_wl, ftb);

    // K7: final conv + BN + SiLU (round-11 schedule)
    gemm_m97_kernel<256, 9, true><<<dim3(32, 2, 8), 256, 0, stream>>>(
        wT, ftb, bnp, bnp + 256, out, 4356L * 256, 256L * 4096, 1);
}